// Round 7
// baseline (85.676 us; speedup 1.0000x reference)
//
#include <hip/hip_runtime.h>

#define N_TEX 65536
#define C 16
#define U 4194304
#define ILP 4

typedef float    f32x4 __attribute__((ext_vector_type(4)));
typedef int      i32x4 __attribute__((ext_vector_type(4)));
typedef _Float16 f16x4 __attribute__((ext_vector_type(4)));

// ---------------------------------------------------------------------------
// Convert fp32 texture (4 MiB) -> fp16 (2 MiB) in d_ws.
// ---------------------------------------------------------------------------
__global__ __launch_bounds__(256) void convert_kernel(
    const f32x4* __restrict__ in, f16x4* __restrict__ out16)
{
    const int i = blockIdx.x * 256 + threadIdx.x;
    f32x4 v = __builtin_nontemporal_load(&in[i]);
    f16x4 h;
    h.x = (_Float16)v.x; h.y = (_Float16)v.y;
    h.z = (_Float16)v.z; h.w = (_Float16)v.w;
    out16[i] = h;
}

// ---------------------------------------------------------------------------
// Cheap warm kernel: 2,048 blocks (8x fewer than R6 -> ~8x less dispatch
// cost), XCD-aware. Warm block b (XCD b%8) covers:
//   - param for the 8 sampler blocks s = (b%8) + 8*((b>>3)*8 + i), i in [0,8)
//     (sampler block s reads f32x4 units s*16 + m + k*262144, m in [0,16),
//      k in [0,4)) -> 8 KiB per warm block, 2 float4 loads per thread.
//   - texture chunk [(b>>3)*8 KiB, +8 KiB): per XCD its 256 blocks cover the
//     FULL 2 MiB texture, so every XCD's L2 holds a complete copy.
// Values kept live via asm sink; no stores.
// ---------------------------------------------------------------------------
__global__ __launch_bounds__(256) void warm_kernel(
    const i32x4* __restrict__ texv, const f32x4* __restrict__ paramv)
{
    const int b = blockIdx.x;
    const int t = threadIdx.x;

    // param: thread group of 32 covers one sampler block's 256 floats
    const int i = t >> 5;                   // which of 8 sampler blocks
    const int g = t & 31;
    const int s = (b & 7) + 8 * ((b >> 3) * 8 + i);
    const int k0 = g >> 4;                  // k in {0,1} then {2,3}
    const int m  = g & 15;
    f32x4 p0 = paramv[s * 16 + m + k0 * 262144];
    f32x4 p1 = paramv[s * 16 + m + (k0 + 2) * 262144];

    // texture: 8 KiB chunk per block, 32 B per thread
    const int cbase = (b >> 3) * 512 + t * 2;
    i32x4 t0 = texv[cbase];
    i32x4 t1 = texv[cbase + 1];

    asm volatile("" :: "v"(p0), "v"(p1), "v"(t0), "v"(t1));
}

// ---------------------------------------------------------------------------
// Sampler (unchanged): 4 lanes per sample, fp16 texture, ILP=4,
// nontemporal param loads + output stores.
// ---------------------------------------------------------------------------
__global__ __launch_bounds__(256) void sampler1d_kernel(
    const f16x4* __restrict__ tex16, const float* __restrict__ param,
    f32x4* __restrict__ out)
{
    const int NT  = (U * 4) / ILP;
    const int tid = blockIdx.x * 256 + threadIdx.x;
    const int q   = tid & 3;

    float p[ILP];
#pragma unroll
    for (int k = 0; k < ILP; ++k)
        p[k] = __builtin_nontemporal_load(&param[(tid + k * NT) >> 2]);

    float w[ILP];
    f16x4 a[ILP], b[ILP];
#pragma unroll
    for (int k = 0; k < ILP; ++k) {
        const float t = p[k] * (float)(N_TEX - 1);
        float f = floorf(t);
        f = fminf(fmaxf(f, 0.0f), (float)(N_TEX - 1));
        const int i0 = (int)f;
        const int i1 = min(i0 + 1, N_TEX - 1);
        w[k] = t - f;
        a[k] = tex16[i0 * 4 + q];
        b[k] = tex16[i1 * 4 + q];
    }

#pragma unroll
    for (int k = 0; k < ILP; ++k) {
        const float wk = w[k], iw = 1.0f - wk;
        f32x4 r;
        r.x = (float)a[k].x * iw + (float)b[k].x * wk;
        r.y = (float)a[k].y * iw + (float)b[k].y * wk;
        r.z = (float)a[k].z * iw + (float)b[k].z * wk;
        r.w = (float)a[k].w * iw + (float)b[k].w * wk;
        __builtin_nontemporal_store(r, &out[tid + k * NT]);
    }
}

extern "C" void kernel_launch(void* const* d_in, const int* in_sizes, int n_in,
                              void* d_out, int out_size, void* d_ws, size_t ws_size,
                              hipStream_t stream) {
    const f32x4* tex32 = (const f32x4*)d_in[0];
    const float* param = (const float*)d_in[1];
    f32x4*       out   = (f32x4*)d_out;
    f16x4*       tex16 = (f16x4*)d_ws;     // 2 MiB scratch

    const int total_thr = (U * 4) / ILP;   // 4,194,304 -> 16,384 blocks

    convert_kernel<<<(N_TEX * C / 4) / 256, 256, 0, stream>>>(tex32, tex16);
    warm_kernel<<<2048, 256, 0, stream>>>((const i32x4*)tex16, (const f32x4*)param);
    sampler1d_kernel<<<total_thr / 256, 256, 0, stream>>>(tex16, param, out);
}